// Round 2
// baseline (85.916 us; speedup 1.0000x reference)
//
#include <hip/hip_runtime.h>

#define BINS 10
#define HSTRIDE 11   // per-thread histogram stride; gcd(11,32)=1 spreads banks
#define BLOCK 256

// ---------------------------------------------------------------------------
// ws layout (doubles): [0..9] counts, [10..19] bce sums
// ---------------------------------------------------------------------------

__global__ void ghmc_init(double* ws) {
    int i = threadIdx.x;
    if (i < 2 * BINS) ws[i] = 0.0;
}

__device__ __forceinline__ void process_logit(float x, float tg, float* cnt, float* sum) {
    // shared exp(-|x|) serves both sigmoid and the stable BCE log-term
    float ax = fabsf(x);
    float e  = expf(-ax);
    float sp = 1.0f + e;
    float sig = (x >= 0.0f) ? (1.0f / sp) : (e / sp);
    float g = fabsf(sig - tg);
    int b = (int)(g * 10.0f);
    b = b > (BINS - 1) ? (BINS - 1) : b;
    float bce = fmaxf(x, 0.0f) - x * tg + log1pf(e);
    cnt[b] += 1.0f;
    sum[b] += bce;
}

__global__ __launch_bounds__(BLOCK) void ghmc_main(
    const float4* __restrict__ pred2,   // one float4 = 2 rows' logits
    const int4*   __restrict__ tgt4,    // one int4   = 4 rows' targets (int32!)
    double* __restrict__ ws,
    int nQuads, int nRows)
{
    __shared__ float h_cnt[BLOCK * HSTRIDE];
    __shared__ float h_sum[BLOCK * HSTRIDE];
    const int tid = threadIdx.x;
    float* cnt = &h_cnt[tid * HSTRIDE];
    float* sum = &h_sum[tid * HSTRIDE];
#pragma unroll
    for (int b = 0; b < BINS; ++b) { cnt[b] = 0.0f; sum[b] = 0.0f; }

    const int stride = gridDim.x * blockDim.x;
    const int gid = blockIdx.x * blockDim.x + tid;

    for (int i = gid; i < nQuads; i += stride) {
        float4 pa = pred2[2 * i + 0];   // rows 4i, 4i+1
        float4 pb = pred2[2 * i + 1];   // rows 4i+2, 4i+3
        int4 t = tgt4[i];
        process_logit(pa.x, (t.x == 0) ? 1.0f : 0.0f, cnt, sum);
        process_logit(pa.y, (t.x == 1) ? 1.0f : 0.0f, cnt, sum);
        process_logit(pa.z, (t.y == 0) ? 1.0f : 0.0f, cnt, sum);
        process_logit(pa.w, (t.y == 1) ? 1.0f : 0.0f, cnt, sum);
        process_logit(pb.x, (t.z == 0) ? 1.0f : 0.0f, cnt, sum);
        process_logit(pb.y, (t.z == 1) ? 1.0f : 0.0f, cnt, sum);
        process_logit(pb.z, (t.w == 0) ? 1.0f : 0.0f, cnt, sum);
        process_logit(pb.w, (t.w == 1) ? 1.0f : 0.0f, cnt, sum);
    }

    // scalar tail for nRows % 4 leftover rows (N is divisible by 4 here; defensive)
    if (gid == 0) {
        const float* predf = (const float*)pred2;
        const int*   tgtf  = (const int*)tgt4;
        for (int r = nQuads * 4; r < nRows; ++r) {
            int t = tgtf[r];
            process_logit(predf[2 * r + 0], (t == 0) ? 1.0f : 0.0f, cnt, sum);
            process_logit(predf[2 * r + 1], (t == 1) ? 1.0f : 0.0f, cnt, sum);
        }
    }

    __syncthreads();

    // tree-reduce the 256 private histograms down to thread 0's row
    for (int s = BLOCK / 2; s > 0; s >>= 1) {
        if (tid < s) {
#pragma unroll
            for (int b = 0; b < BINS; ++b) {
                h_cnt[tid * HSTRIDE + b] += h_cnt[(tid + s) * HSTRIDE + b];
                h_sum[tid * HSTRIDE + b] += h_sum[(tid + s) * HSTRIDE + b];
            }
        }
        __syncthreads();
    }

    if (tid < BINS) {
        atomicAdd(&ws[tid],        (double)h_cnt[tid]);
        atomicAdd(&ws[BINS + tid], (double)h_sum[tid]);
    }
}

__global__ void ghmc_final(const double* __restrict__ ws, float* __restrict__ out) {
    if (threadIdx.x == 0) {
        int nz = 0;
        double acc = 0.0;
#pragma unroll
        for (int b = 0; b < BINS; ++b) {
            double c = ws[b];
            if (c > 0.0) { nz++; acc += ws[BINS + b] / c; }
        }
        double loss = (nz > 0) ? (acc / (double)nz) : 0.0;
        out[0] = (float)loss;
    }
}

extern "C" void kernel_launch(void* const* d_in, const int* in_sizes, int n_in,
                              void* d_out, int out_size, void* d_ws, size_t ws_size,
                              hipStream_t stream) {
    const float* pred = (const float*)d_in[0];   // [N,2] float32
    const int* target = (const int*)d_in[1];     // [N] int32 (harness lowers int64)
    const int nRows = in_sizes[1];
    const int nQuads = nRows / 4;

    double* ws = (double*)d_ws;
    float* out = (float*)d_out;

    ghmc_init<<<1, 64, 0, stream>>>(ws);

    int blocks = 2048;
    ghmc_main<<<blocks, BLOCK, 0, stream>>>(
        (const float4*)pred, (const int4*)target, ws, nQuads, nRows);

    ghmc_final<<<1, 64, 0, stream>>>(ws, out);
}

// Round 3
// 30.997 us; speedup vs baseline: 2.7717x; 2.7717x over previous
//
#include <hip/hip_runtime.h>

#define BINS 10
#define BLOCK 256
#define GRID 2048

#define LOG2E 1.44269504088896340736f
#define LN2   0.69314718055994530942f

// ---------------------------------------------------------------------------
// Identity used throughout: for a logit x with one-hot target bit tg,
//   y   = tg ? -x : x
//   g   = |sigmoid(x) - tg| = sigmoid(y)
//   bce = max(x,0) - x*tg + log1p(exp(-|x|)) = softplus(y)
// Both come from one exp: t = e^{-|y|}, d = 1+t:
//   sigmoid(y)  = (y>=0) ? 1/d : t/d
//   softplus(y) = max(y,0) + ln(d)
// ---------------------------------------------------------------------------

__global__ void ghmc_init(double* ws) {
    int i = threadIdx.x;
    if (i < 2 * BINS) ws[i] = 0.0;
}

// hist layout [BINS][BLOCK] float2: column = tid -> bank pair (2*tid)%32,
// bin offset = BLOCK*8 = 2048 B == 0 mod (32 banks * 4 B) -> conflict-free b64.
__device__ __forceinline__ void proc(float y, float2* __restrict__ hbase) {
    float a  = -fabsf(y) * LOG2E;
    float t  = __builtin_amdgcn_exp2f(a);          // e^{-|y|}
    float d  = 1.0f + t;
    float r  = __builtin_amdgcn_rcpf(d);           // 1/d  (~1 ulp)
    float lg = __builtin_amdgcn_logf(d);           // log2(d)
    float sp = fmaf(lg, LN2, fmaxf(y, 0.0f));      // softplus(y) == bce
    float sg = (y >= 0.0f) ? r : t * r;            // sigmoid(y) == g
    int b = (int)(sg * 10.0f);
    b = b > (BINS - 1) ? (BINS - 1) : b;
    float2* h = hbase + (b << 8);                  // + b*BLOCK
    float2 v = *h;                                 // ds_read_b64
    v.x += 1.0f;
    v.y += sp;
    *h = v;                                        // ds_write_b64
}

__device__ __forceinline__ void proc_row(float x0, float x1, int t,
                                         float2* __restrict__ hbase) {
    // class0 flips iff t==0, class1 flips iff t==1 (t is 0 or 1)
    unsigned s0 = (unsigned)(t ^ 1) << 31;
    unsigned s1 = s0 ^ 0x80000000u;
    proc(__uint_as_float(__float_as_uint(x0) ^ s0), hbase);
    proc(__uint_as_float(__float_as_uint(x1) ^ s1), hbase);
}

template <int WRITE_MODE>  // 0 = per-block partials (deterministic), 1 = double atomics
__global__ __launch_bounds__(BLOCK, 4) void ghmc_main(
    const float4* __restrict__ pred4,   // one float4 = 2 rows' logits
    const int4*   __restrict__ tgt4,    // one int4   = 4 rows' targets (int32)
    float2* __restrict__ partials,      // [GRID][BINS] (mode 0)
    double* __restrict__ wsd,           // [2*BINS]     (mode 1)
    int nQuads, int nRows)
{
    __shared__ float2 hist[BINS][BLOCK];
    const int tid = threadIdx.x;
#pragma unroll
    for (int b = 0; b < BINS; ++b) hist[b][tid] = make_float2(0.f, 0.f);
    // no sync needed: each thread touches only its own column until reduction

    float2* hbase = &hist[0][tid];

    for (int i = blockIdx.x * BLOCK + tid; i < nQuads; i += GRID * BLOCK) {
        float4 pa = pred4[2 * i + 0];   // rows 4i, 4i+1
        float4 pb = pred4[2 * i + 1];   // rows 4i+2, 4i+3
        int4   tq = tgt4[i];
        proc_row(pa.x, pa.y, tq.x, hbase);
        proc_row(pa.z, pa.w, tq.y, hbase);
        proc_row(pb.x, pb.y, tq.z, hbase);
        proc_row(pb.z, pb.w, tq.w, hbase);
    }

    // defensive scalar tail (N divisible by 4 here)
    if (blockIdx.x == 0 && tid == 0) {
        const float* pf = (const float*)pred4;
        const int*   tf = (const int*)tgt4;
        for (int r = nQuads * 4; r < nRows; ++r)
            proc_row(pf[2 * r], pf[2 * r + 1], tf[r], hbase);
    }

    __syncthreads();

    // 256 -> 128 -> 64 in LDS, then wave-0 shuffle reduce
    if (tid < 128) {
#pragma unroll
        for (int b = 0; b < BINS; ++b) {
            float2 x = hist[b][tid], y = hist[b][tid + 128];
            hist[b][tid] = make_float2(x.x + y.x, x.y + y.y);
        }
    }
    __syncthreads();
    if (tid < 64) {
        float cx[BINS], cy[BINS];
#pragma unroll
        for (int b = 0; b < BINS; ++b) {
            float2 x = hist[b][tid], y = hist[b][tid + 64];
            cx[b] = x.x + y.x;
            cy[b] = x.y + y.y;
        }
#pragma unroll
        for (int off = 32; off > 0; off >>= 1) {
#pragma unroll
            for (int b = 0; b < BINS; ++b) {
                cx[b] += __shfl_down(cx[b], off, 64);
                cy[b] += __shfl_down(cy[b], off, 64);
            }
        }
        if (tid == 0) {
            if (WRITE_MODE == 0) {
#pragma unroll
                for (int b = 0; b < BINS; ++b)
                    partials[blockIdx.x * BINS + b] = make_float2(cx[b], cy[b]);
            } else {
#pragma unroll
                for (int b = 0; b < BINS; ++b) {
                    atomicAdd(&wsd[b],        (double)cx[b]);
                    atomicAdd(&wsd[BINS + b], (double)cy[b]);
                }
            }
        }
    }
}

__global__ __launch_bounds__(BLOCK) void ghmc_final_grid(
    const float2* __restrict__ partials, float* __restrict__ out, int nb)
{
    __shared__ double2 red[BINS][BLOCK];   // 40 KiB
    const int tid = threadIdx.x;
    double cx[BINS], cy[BINS];
#pragma unroll
    for (int b = 0; b < BINS; ++b) { cx[b] = 0.0; cy[b] = 0.0; }

    for (int p = tid; p < nb; p += BLOCK) {
#pragma unroll
        for (int b = 0; b < BINS; ++b) {
            float2 v = partials[p * BINS + b];
            cx[b] += (double)v.x;
            cy[b] += (double)v.y;
        }
    }
#pragma unroll
    for (int b = 0; b < BINS; ++b) red[b][tid] = make_double2(cx[b], cy[b]);
    __syncthreads();
    if (tid < 128) {
#pragma unroll
        for (int b = 0; b < BINS; ++b) {
            double2 x = red[b][tid], y = red[b][tid + 128];
            red[b][tid] = make_double2(x.x + y.x, x.y + y.y);
        }
    }
    __syncthreads();
    if (tid < 64) {
        double dx[BINS], dy[BINS];
#pragma unroll
        for (int b = 0; b < BINS; ++b) {
            double2 x = red[b][tid], y = red[b][tid + 64];
            dx[b] = x.x + y.x;
            dy[b] = x.y + y.y;
        }
#pragma unroll
        for (int off = 32; off > 0; off >>= 1) {
#pragma unroll
            for (int b = 0; b < BINS; ++b) {
                dx[b] += __shfl_down(dx[b], off, 64);
                dy[b] += __shfl_down(dy[b], off, 64);
            }
        }
        if (tid == 0) {
            int nz = 0;
            double acc = 0.0;
#pragma unroll
            for (int b = 0; b < BINS; ++b) {
                if (dx[b] > 0.0) { nz++; acc += dy[b] / dx[b]; }
            }
            out[0] = (float)((nz > 0) ? (acc / (double)nz) : 0.0);
        }
    }
}

__global__ void ghmc_final_atomic(const double* __restrict__ ws, float* __restrict__ out) {
    if (threadIdx.x == 0) {
        int nz = 0;
        double acc = 0.0;
#pragma unroll
        for (int b = 0; b < BINS; ++b) {
            double c = ws[b];
            if (c > 0.0) { nz++; acc += ws[BINS + b] / c; }
        }
        out[0] = (float)((nz > 0) ? (acc / (double)nz) : 0.0);
    }
}

extern "C" void kernel_launch(void* const* d_in, const int* in_sizes, int n_in,
                              void* d_out, int out_size, void* d_ws, size_t ws_size,
                              hipStream_t stream) {
    const float* pred = (const float*)d_in[0];   // [N,2] float32
    const int* target = (const int*)d_in[1];     // [N] int32 (harness lowers int64)
    const int nRows = in_sizes[1];
    const int nQuads = nRows / 4;
    float* out = (float*)d_out;

    const size_t need = (size_t)GRID * BINS * sizeof(float2);  // 160 KiB
    if (ws_size >= need) {
        float2* partials = (float2*)d_ws;
        ghmc_main<0><<<GRID, BLOCK, 0, stream>>>(
            (const float4*)pred, (const int4*)target, partials, nullptr, nQuads, nRows);
        ghmc_final_grid<<<1, BLOCK, 0, stream>>>(partials, out, GRID);
    } else {
        double* wsd = (double*)d_ws;
        ghmc_init<<<1, 64, 0, stream>>>(wsd);
        ghmc_main<1><<<GRID, BLOCK, 0, stream>>>(
            (const float4*)pred, (const int4*)target, nullptr, wsd, nQuads, nRows);
        ghmc_final_atomic<<<1, 64, 0, stream>>>(wsd, out);
    }
}